// Round 3
// baseline (131.575 us; speedup 1.0000x reference)
//
#include <hip/hip_runtime.h>

// Conv1d: out[b,c,i] = sum_{k=0}^{127} x[b,c,i+k] * w[k]
// B=32, C=512, L=4096, KL=128 -> rows=16384, Lo=3969.
//
// bf16 MFMA band conv with 32x32x16 tiles (halves LDS read traffic vs 16x16),
// conflict-free padded LDS (addr = e + 8*(e>>5)), float4 output stores.
//   D[m][n] = sum_k A[m][k]*B[k][n] = out[i0 + 32n + m]
//   A[m][k]  = w[k-m]        (band, 0<=k-m<128, else 0)  -> registers
//   B[k][n]  = x[i0+32n+k]   (k=0..159)                  -> LDS
// 10x mfma_f32_32x32x16_bf16 per 1024 outputs. HBM floor ~84 us @ 6.3 TB/s.

#define NROWS 16384
#define LIN   4096
#define KLEN  128
#define LOUT  3969           // LIN - KLEN + 1
#define KTOT  160            // band K extent (>= 128 + 31), 10 steps of 16
#define NSTEP 10
#define RPB   2              // rows per block
#define XELEMS (LIN + KTOT)  // 4256 staged elems per row (incl. zero tail)
#define ROWSZ 5312           // padded LDS elems per row: pmap(4255)+1 rounded to 8

typedef __attribute__((ext_vector_type(8))) short bf16x8;
typedef __attribute__((ext_vector_type(16))) float f32x16;

__device__ __forceinline__ unsigned short f2bf(float f) {
    // round-to-nearest-even fp32 -> bf16 (inputs finite)
    unsigned int u = __float_as_uint(f);
    u += 0x7FFFu + ((u >> 16) & 1u);
    return (unsigned short)(u >> 16);
}

// bank-decorrelating pad: +8 elems (16B) after every 32 elems (64B)
__device__ __forceinline__ int pmap(int e) { return e + ((e >> 5) << 3); }

__global__ __launch_bounds__(256, 4)
void conv1d_mfma(const float* __restrict__ x, const float* __restrict__ w,
                 float* __restrict__ out) {
    __shared__ __align__(16) unsigned short xs[RPB * ROWSZ];  // 21248 B

    const int t = threadIdx.x;
    const long long row0 = (long long)blockIdx.x * RPB;

    const int lane = t & 63;
    const int m31  = lane & 31;   // A row m and B col n (shared lane field)
    const int h    = lane >> 5;   // K half-chunk
    const int wv   = t >> 6;      // wave 0..3 -> output tile wv per row

    // ---- A fragments (weight band) from global w; overlaps x-load latency ----
    // wf[kb][j] = w[16kb + 8h + j - m31], 0 if index outside [0,128)
    bf16x8 wf[NSTEP];
    #pragma unroll
    for (int kb = 0; kb < NSTEP; ++kb) {
        #pragma unroll
        for (int j = 0; j < 8; ++j) {
            const int d  = 16 * kb + 8 * h + j - m31;
            const int dc = d < 0 ? 0 : (d > KLEN - 1 ? KLEN - 1 : d);
            float val = w[dc];
            if ((unsigned)d >= (unsigned)KLEN) val = 0.f;
            wf[kb][j] = (short)f2bf(val);
        }
    }

    // ---- stage RPB rows: fp32 -> bf16 into padded LDS ----
    #pragma unroll
    for (int r = 0; r < RPB; ++r) {
        const float* xr = x + (row0 + r) * LIN;
        float4 v[4];
        #pragma unroll
        for (int j = 0; j < 4; ++j)
            v[j] = *reinterpret_cast<const float4*>(xr + 4 * (t + 256 * j));
        #pragma unroll
        for (int j = 0; j < 4; ++j) {
            const int e = 4 * (t + 256 * j);
            ushort4 p;
            p.x = f2bf(v[j].x); p.y = f2bf(v[j].y);
            p.z = f2bf(v[j].z); p.w = f2bf(v[j].w);
            *reinterpret_cast<ushort4*>(&xs[r * ROWSZ + pmap(e)]) = p;
        }
    }
    // zero the 160-elem tails (40 ushort4 per row); wave r handles row r
    if (wv < RPB && lane < 40) {
        const int e = LIN + 4 * lane;
        ushort4 z; z.x = 0; z.y = 0; z.z = 0; z.w = 0;
        *reinterpret_cast<ushort4*>(&xs[wv * ROWSZ + pmap(e)]) = z;
    }
    __syncthreads();

    // ---- compute: each wave does tile wv (1024 outputs) of each row ----
    const int i0 = 1024 * wv;
    #pragma unroll
    for (int r = 0; r < RPB; ++r) {
        // B base (padded elems): pmap(i0 + 32*m31 + 8h) with aligned decomposition
        const int abase = r * ROWSZ + i0 + ((i0 >> 5) << 3) + 40 * m31 + 8 * h;
        f32x16 acc = {0.f, 0.f, 0.f, 0.f, 0.f, 0.f, 0.f, 0.f,
                      0.f, 0.f, 0.f, 0.f, 0.f, 0.f, 0.f, 0.f};
        #pragma unroll
        for (int kb = 0; kb < NSTEP; ++kb) {
            const int off = 16 * kb + ((kb >> 1) << 3);  // pmap of +16*kb
            const bf16x8 xf = *reinterpret_cast<const bf16x8*>(&xs[abase + off]);
            acc = __builtin_amdgcn_mfma_f32_32x32x16_bf16(wf[kb], xf, acc, 0, 0, 0);
        }
        // D: n = m31, m = (reg&3) + 8*(reg>>2) + 4h -> out[i0 + 32n + m]
        float* outr = out + (row0 + r) * LOUT;
        const int obase = i0 + 32 * m31 + 4 * h;
        #pragma unroll
        for (int q = 0; q < 4; ++q) {
            const int off = obase + 8 * q;
            if (off + 3 < LOUT) {
                float4 s;
                s.x = acc[4 * q + 0]; s.y = acc[4 * q + 1];
                s.z = acc[4 * q + 2]; s.w = acc[4 * q + 3];
                *reinterpret_cast<float4*>(outr + off) = s;
            } else {
                #pragma unroll
                for (int rr = 0; rr < 4; ++rr)
                    if (off + rr < LOUT) outr[off + rr] = acc[4 * q + rr];
            }
        }
    }
}

extern "C" void kernel_launch(void* const* d_in, const int* in_sizes, int n_in,
                              void* d_out, int out_size, void* d_ws, size_t ws_size,
                              hipStream_t stream) {
    const float* x = (const float*)d_in[0];
    const float* w = (const float*)d_in[1];
    float* o = (float*)d_out;
    hipLaunchKernelGGL(conv1d_mfma, dim3(NROWS / RPB), dim3(256), 0, stream, x, w, o);
}

// Round 4
// 131.010 us; speedup vs baseline: 1.0043x; 1.0043x over previous
//
#include <hip/hip_runtime.h>

// Conv1d: out[b,c,i] = sum_{k=0}^{127} x[b,c,i+k] * w[k]
// B=32, C=512, L=4096, KL=128 -> rows=16384, Lo=3969.
//
// bf16 MFMA band conv (16x16x32), PERSISTENT pipelined version:
// 1024 blocks (4/CU), 8 row-pairs per block, double-buffered LDS + regs.
// Loads for iter t+2 are issued before compute of iter t -> HBM reads stay
// in flight through every compute phase (fixes bursty/phase-locked streaming).
//   D[m][n] = sum_k A[m][k]*Bband[k][n], A[m][k]=x[i0+16m+k] (k=0..159),
//   Bband[k][n] = w[k-n] if 0<=k-n<128 else 0. 5 MFMA per 256 outputs.
// HBM floor ~528 MB -> 84 us @ 6.3 TB/s.

#define NROWS 16384
#define LIN   4096
#define KLEN  128
#define LOUT  3969           // LIN - KLEN + 1
#define KTOT  160            // band K extent
#define NSTEP 5              // KTOT / 32
#define XELEMS (LIN + KTOT)  // 4256 staged elems per row (incl. zero tail)
#define RPB   2              // rows per block-iteration
#define GRID  1024           // 4 blocks/CU exactly
#define NIT   ((NROWS / RPB) / GRID)  // 8 iterations per block

typedef __attribute__((ext_vector_type(8))) short bf16x8;
typedef __attribute__((ext_vector_type(4))) float f32x4;

__device__ __forceinline__ unsigned short f2bf(float f) {
    // round-to-nearest-even fp32 -> bf16 (inputs finite)
    unsigned int u = __float_as_uint(f);
    u += 0x7FFFu + ((u >> 16) & 1u);
    return (unsigned short)(u >> 16);
}

__global__ __launch_bounds__(256, 4)
void conv1d_mfma(const float* __restrict__ x, const float* __restrict__ w,
                 float* __restrict__ out) {
    __shared__ __align__(16) unsigned short xs[2][RPB][XELEMS];  // 34048 B

    const int t    = threadIdx.x;
    const int lane = t & 63;
    const int g    = lane >> 4;   // 0..3
    const int nn   = lane & 15;   // 0..15
    const int wv   = t >> 6;      // wave 0..3
    const int bid  = blockIdx.x;

    // ---- B fragments (weight band) straight from global w (L1-hot) ----
    // bfrag[kb][j] = w[kb*32 + 8g + j - nn] (0 outside [0,128))
    bf16x8 bfrag[NSTEP];
    #pragma unroll
    for (int kb = 0; kb < NSTEP; ++kb) {
        #pragma unroll
        for (int j = 0; j < 8; ++j) {
            const int d  = kb * 32 + 8 * g + j - nn;
            const int dc = d < 0 ? 0 : (d > KLEN - 1 ? KLEN - 1 : d);
            float val = w[dc];
            if ((unsigned)d >= (unsigned)KLEN) val = 0.f;
            bfrag[kb][j] = (short)f2bf(val);
        }
    }

    auto load_rows = [&](float4 (&v)[RPB][4], int it) {
        const float* xr = x + (long long)(bid + it * GRID) * (RPB * LIN);
        #pragma unroll
        for (int r = 0; r < RPB; ++r)
            #pragma unroll
            for (int j = 0; j < 4; ++j)
                v[r][j] = *reinterpret_cast<const float4*>(xr + r * LIN + 4 * (t + 256 * j));
    };

    auto stage = [&](unsigned short (&dst)[RPB][XELEMS], const float4 (&v)[RPB][4]) {
        #pragma unroll
        for (int r = 0; r < RPB; ++r)
            #pragma unroll
            for (int j = 0; j < 4; ++j) {
                const int e = 4 * (t + 256 * j);
                ushort4 p;
                p.x = f2bf(v[r][j].x); p.y = f2bf(v[r][j].y);
                p.z = f2bf(v[r][j].z); p.w = f2bf(v[r][j].w);
                *reinterpret_cast<ushort4*>(&dst[r][e]) = p;
            }
    };

    auto compute_store = [&](const unsigned short (&src)[RPB][XELEMS], int it) {
        const long long pr = bid + (long long)it * GRID;
        #pragma unroll
        for (int r = 0; r < RPB; ++r) {
            float* outr = out + (pr * RPB + r) * LOUT;
            #pragma unroll
            for (int tt = 0; tt < 4; ++tt) {
                const int i0 = 256 * (wv + 4 * tt);
                const unsigned short* abase = &src[r][i0 + 16 * nn + 8 * g];
                f32x4 acc = {0.f, 0.f, 0.f, 0.f};
                #pragma unroll
                for (int kb = 0; kb < NSTEP; ++kb) {
                    const bf16x8 af = *reinterpret_cast<const bf16x8*>(abase + 32 * kb);
                    acc = __builtin_amdgcn_mfma_f32_16x16x32_bf16(af, bfrag[kb], acc, 0, 0, 0);
                }
                // D: col n = lane&15, row m = 4*(lane>>4)+rr -> contiguous 256B/instr
                #pragma unroll
                for (int rr = 0; rr < 4; ++rr) {
                    const int oi = i0 + 64 * g + 16 * rr + nn;
                    if (oi < LOUT) outr[oi] = acc[rr];
                }
            }
        }
    };

    float4 va[RPB][4], vb[RPB][4];

    // ---- prologue: stage iter 0, issue loads for iter 1, zero tails ----
    load_rows(va, 0);
    stage(xs[0], va);
    load_rows(va, 1);
    if (t < 160) {  // 2 bufs x 2 rows x 40 ushort4 tails, zeroed once
        const int b = t / 80, rem = t - 80 * b;
        const int r = rem / 40, q = rem - 40 * r;
        ushort4 z; z.x = 0; z.y = 0; z.z = 0; z.w = 0;
        *reinterpret_cast<ushort4*>(&xs[b][r][LIN + 4 * q]) = z;
    }
    __syncthreads();

    // ---- main pipeline: one barrier per iteration, loads 2 iters ahead ----
    for (int tp = 0; tp < NIT / 2; ++tp) {
        const int t0 = 2 * tp, t1 = 2 * tp + 1;
        if (t0 + 2 < NIT) load_rows(vb, t0 + 2);   // in flight during compute
        compute_store(xs[0], t0);
        stage(xs[1], va);                          // va = rows(t0+1), long done
        __syncthreads();
        if (t1 + 2 < NIT) load_rows(va, t1 + 2);
        compute_store(xs[1], t1);
        if (t1 + 1 < NIT) stage(xs[0], vb);
        __syncthreads();
    }
}

extern "C" void kernel_launch(void* const* d_in, const int* in_sizes, int n_in,
                              void* d_out, int out_size, void* d_ws, size_t ws_size,
                              hipStream_t stream) {
    const float* x = (const float*)d_in[0];
    const float* w = (const float*)d_in[1];
    float* o = (float*)d_out;
    hipLaunchKernelGGL(conv1d_mfma, dim3(GRID), dim3(256), 0, stream, x, w, o);
}

// Round 5
// 120.427 us; speedup vs baseline: 1.0926x; 1.0879x over previous
//
#include <hip/hip_runtime.h>
#include <hip/hip_bf16.h>

// Conv1d: out[b,c,i] = sum_{k=0}^{127} x[b,c,i+k] * w[k]
// B=32, C=512, L=4096, KL=128 -> rows=16384, Lo=3969.
//
// bf16 MFMA band conv (16x16x32), round-2 proven structure + three levers:
//  - launch_bounds(256,8): 32 waves/CU (VGPR<=64, 17KB LDS -> 8 blocks/CU)
//  - nontemporal x loads (single-use read stream; stop thrashing write lines)
//  - v_cvt_pk_bf16_f32 staging conversion (1 op / 2 elems)
// HBM floor ~528 MB -> 84 us @ 6.3 TB/s.

#define NROWS 16384
#define LIN   4096
#define KLEN  128
#define LOUT  3969           // LIN - KLEN + 1
#define KTOT  160            // band K extent
#define NSTEP 5              // KTOT / 32
#define XELEMS (LIN + KTOT)  // 4256 staged elems per row (incl. zero tail)
#define RPB   2              // rows per block

typedef __attribute__((ext_vector_type(8))) short bf16x8;
typedef __attribute__((ext_vector_type(4))) float f32x4;

__device__ __forceinline__ unsigned short f2bf(float f) {
    // round-to-nearest-even fp32 -> bf16 (scalar path, weights only)
    unsigned int u = __float_as_uint(f);
    u += 0x7FFFu + ((u >> 16) & 1u);
    return (unsigned short)(u >> 16);
}

__device__ __forceinline__ unsigned int pack_bf2(float a, float b) {
    float2 f; f.x = a; f.y = b;
    __hip_bfloat162 h = __float22bfloat162_rn(f);   // v_cvt_pk_bf16_f32
    unsigned int u; __builtin_memcpy(&u, &h, 4);
    return u;
}

__global__ __launch_bounds__(256, 8)
void conv1d_mfma(const float* __restrict__ x, const float* __restrict__ w,
                 float* __restrict__ out) {
    __shared__ __align__(16) unsigned short xs[RPB][XELEMS];  // 17024 B

    const int t = threadIdx.x;
    const long long row0 = (long long)blockIdx.x * RPB;

    const int lane = t & 63;
    const int g    = lane >> 4;   // 0..3
    const int nn   = lane & 15;   // 0..15
    const int wv   = t >> 6;      // wave 0..3

    // ---- B fragments (weight band) straight from global w (L1-hot) ----
    // bfrag[kb][j] = w[kb*32 + 8g + j - nn] (0 outside [0,128))
    bf16x8 bfrag[NSTEP];
    #pragma unroll
    for (int kb = 0; kb < NSTEP; ++kb) {
        #pragma unroll
        for (int j = 0; j < 8; ++j) {
            const int d  = kb * 32 + 8 * g + j - nn;
            const int dc = d < 0 ? 0 : (d > KLEN - 1 ? KLEN - 1 : d);
            float val = w[dc];
            if ((unsigned)d >= (unsigned)KLEN) val = 0.f;
            bfrag[kb][j] = (short)f2bf(val);
        }
    }

    // ---- stage rows: nt float4 loads, cvt_pk to bf16, LDS ----
    #pragma unroll
    for (int r = 0; r < RPB; ++r) {
        const float* xr = x + (row0 + r) * LIN;
        f32x4 v[4];
        #pragma unroll
        for (int j = 0; j < 4; ++j)
            v[j] = __builtin_nontemporal_load(
                       reinterpret_cast<const f32x4*>(xr + 4 * (t + 256 * j)));
        #pragma unroll
        for (int j = 0; j < 4; ++j) {
            uint2 p;
            p.x = pack_bf2(v[j][0], v[j][1]);
            p.y = pack_bf2(v[j][2], v[j][3]);
            *reinterpret_cast<uint2*>(&xs[r][4 * (t + 256 * j)]) = p;
        }
    }
    // zero the 160-elem tails (40 ushort4 per row; different waves per row)
    if (t < 40) {
        ushort4 z; z.x = 0; z.y = 0; z.z = 0; z.w = 0;
        *reinterpret_cast<ushort4*>(&xs[0][LIN + 4 * t]) = z;
    } else if (t >= 64 && t < 104) {
        ushort4 z; z.x = 0; z.y = 0; z.z = 0; z.w = 0;
        *reinterpret_cast<ushort4*>(&xs[1][LIN + 4 * (t - 64)]) = z;
    }
    __syncthreads();   // the only barrier

    // ---- 2 rows x 16 tiles (4 waves x 4 iters each) ----
    #pragma unroll
    for (int r = 0; r < RPB; ++r) {
        float* outr = out + (row0 + r) * LOUT;
        #pragma unroll
        for (int it = 0; it < 4; ++it) {
            const int i0 = 256 * (wv + 4 * it);
            const unsigned short* abase = &xs[r][i0 + 16 * nn + 8 * g];
            f32x4 acc = {0.f, 0.f, 0.f, 0.f};
            #pragma unroll
            for (int kb = 0; kb < NSTEP; ++kb) {
                const bf16x8 af = *reinterpret_cast<const bf16x8*>(abase + 32 * kb);
                acc = __builtin_amdgcn_mfma_f32_16x16x32_bf16(af, bfrag[kb], acc, 0, 0, 0);
            }
            // D: col n = lane&15, row m = 4*(lane>>4)+rr
            #pragma unroll
            for (int rr = 0; rr < 4; ++rr) {
                const int oi = i0 + 64 * g + 16 * rr + nn;
                if (oi < LOUT) outr[oi] = acc[rr];
            }
        }
    }
}

extern "C" void kernel_launch(void* const* d_in, const int* in_sizes, int n_in,
                              void* d_out, int out_size, void* d_ws, size_t ws_size,
                              hipStream_t stream) {
    const float* x = (const float*)d_in[0];
    const float* w = (const float*)d_in[1];
    float* o = (float*)d_out;
    hipLaunchKernelGGL(conv1d_mfma, dim3(NROWS / RPB), dim3(256), 0, stream, x, w, o);
}

// Round 6
// 82.291 us; speedup vs baseline: 1.5989x; 1.4634x over previous
//
#include <hip/hip_runtime.h>
#include <hip/hip_bf16.h>

// Conv1d: out[b,c,i] = sum_{k=0}^{127} x[b,c,i+k] * w[k]
// B=32, C=512, L=4096, KL=128 -> rows=16384, Lo=3969.
//
// bf16 MFMA band conv (16x16x32), round-2 proven structure with SWAPPED
// operands: D'[u][v] = sum_k w[k-u] * x[i0+16v+k] = out[i0+16v+u], so each
// lane's 4 acc regs are 4 CONSECUTIVE outputs -> one nontemporal float4
// store per tile (contiguous 1KB/instr, was 4 strided dword stores).
// Fragment formulas identical to validated round-2 kernel.
// HBM floor ~528 MB -> 84 us @ 6.3 TB/s.

#define NROWS 16384
#define LIN   4096
#define KLEN  128
#define LOUT  3969           // LIN - KLEN + 1
#define KTOT  160            // band K extent
#define NSTEP 5              // KTOT / 32
#define XELEMS (LIN + KTOT)  // 4256 staged elems per row (incl. zero tail)
#define RPB   2              // rows per block

typedef __attribute__((ext_vector_type(8))) short bf16x8;
typedef __attribute__((ext_vector_type(4))) float f32x4;

__device__ __forceinline__ unsigned short f2bf(float f) {
    // round-to-nearest-even fp32 -> bf16 (scalar path, weights only)
    unsigned int u = __float_as_uint(f);
    u += 0x7FFFu + ((u >> 16) & 1u);
    return (unsigned short)(u >> 16);
}

__device__ __forceinline__ unsigned int pack_bf2(float a, float b) {
    float2 f; f.x = a; f.y = b;
    __hip_bfloat162 h = __float22bfloat162_rn(f);   // v_cvt_pk_bf16_f32
    unsigned int u; __builtin_memcpy(&u, &h, 4);
    return u;
}

__global__ __launch_bounds__(256, 4)
void conv1d_mfma(const float* __restrict__ x, const float* __restrict__ w,
                 float* __restrict__ out) {
    __shared__ __align__(16) unsigned short xs[RPB][XELEMS];  // 17024 B

    const int t = threadIdx.x;
    const long long row0 = (long long)blockIdx.x * RPB;

    const int lane = t & 63;
    const int g    = lane >> 4;   // 0..3
    const int nn   = lane & 15;   // 0..15
    const int wv   = t >> 6;      // wave 0..3

    // ---- A' fragments (weight band) straight from global w (L1-hot) ----
    // bfrag[kb][j] = w[kb*32 + 8g + j - nn] (0 outside [0,128))
    bf16x8 bfrag[NSTEP];
    #pragma unroll
    for (int kb = 0; kb < NSTEP; ++kb) {
        #pragma unroll
        for (int j = 0; j < 8; ++j) {
            const int d  = kb * 32 + 8 * g + j - nn;
            const int dc = d < 0 ? 0 : (d > KLEN - 1 ? KLEN - 1 : d);
            float val = w[dc];
            if ((unsigned)d >= (unsigned)KLEN) val = 0.f;
            bfrag[kb][j] = (short)f2bf(val);
        }
    }

    // ---- stage rows: float4 loads, cvt_pk to bf16, LDS ----
    #pragma unroll
    for (int r = 0; r < RPB; ++r) {
        const float* xr = x + (row0 + r) * LIN;
        float4 v[4];
        #pragma unroll
        for (int j = 0; j < 4; ++j)
            v[j] = *reinterpret_cast<const float4*>(xr + 4 * (t + 256 * j));
        #pragma unroll
        for (int j = 0; j < 4; ++j) {
            uint2 p;
            p.x = pack_bf2(v[j].x, v[j].y);
            p.y = pack_bf2(v[j].z, v[j].w);
            *reinterpret_cast<uint2*>(&xs[r][4 * (t + 256 * j)]) = p;
        }
    }
    // zero the 160-elem tails (40 ushort4 per row; waves 0 and 1)
    if (t < 40) {
        ushort4 z; z.x = 0; z.y = 0; z.z = 0; z.w = 0;
        *reinterpret_cast<ushort4*>(&xs[0][LIN + 4 * t]) = z;
    } else if (t >= 64 && t < 104) {
        ushort4 z; z.x = 0; z.y = 0; z.z = 0; z.w = 0;
        *reinterpret_cast<ushort4*>(&xs[1][LIN + 4 * (t - 64)]) = z;
    }
    __syncthreads();   // the only barrier

    // ---- 2 rows x 16 tiles (4 waves x 4 iters each) ----
    #pragma unroll
    for (int r = 0; r < RPB; ++r) {
        float* outr = out + (row0 + r) * LOUT;
        #pragma unroll
        for (int it = 0; it < 4; ++it) {
            const int i0 = 256 * (wv + 4 * it);
            const unsigned short* abase = &xs[r][i0 + 16 * nn + 8 * g];
            f32x4 acc = {0.f, 0.f, 0.f, 0.f};
            #pragma unroll
            for (int kb = 0; kb < NSTEP; ++kb) {
                const bf16x8 xf = *reinterpret_cast<const bf16x8*>(abase + 32 * kb);
                // swapped: A = weight band, B = x tile
                acc = __builtin_amdgcn_mfma_f32_16x16x32_bf16(bfrag[kb], xf, acc, 0, 0, 0);
            }
            // D'[u][v] = out[i0 + 16v + u]; v = nn, u = 4g + rr
            // -> lane writes CONSECUTIVE outputs [i0+16nn+4g .. +3]
            const int off = i0 + 16 * nn + 4 * g;
            if (off + 3 < LOUT) {
                f32x4 s = {acc[0], acc[1], acc[2], acc[3]};
                __builtin_nontemporal_store(s, reinterpret_cast<f32x4*>(outr + off));
            } else {
                #pragma unroll
                for (int rr = 0; rr < 4; ++rr)
                    if (off + rr < LOUT) outr[off + rr] = acc[rr];
            }
        }
    }
}

extern "C" void kernel_launch(void* const* d_in, const int* in_sizes, int n_in,
                              void* d_out, int out_size, void* d_ws, size_t ws_size,
                              hipStream_t stream) {
    const float* x = (const float*)d_in[0];
    const float* w = (const float*)d_in[1];
    float* o = (float*)d_out;
    hipLaunchKernelGGL(conv1d_mfma, dim3(NROWS / RPB), dim3(256), 0, stream, x, w, o);
}